// Round 7
// baseline (3161.417 us; speedup 1.0000x reference)
//
#include <hip/hip_runtime.h>
#include <hip/hip_fp16.h>
#include <hip/hip_bf16.h>

typedef __attribute__((ext_vector_type(8))) short bf16x8;
typedef __attribute__((ext_vector_type(4))) float f32x4;

__device__ __forceinline__ short f2bf(float f) {
    unsigned u = __builtin_bit_cast(unsigned, f);
    unsigned r = (u + 0x7FFFu + ((u >> 16) & 1u)) >> 16;
    return (short)r;
}
__device__ __forceinline__ float fast_rcp(float x) {
    return __builtin_amdgcn_rcpf(x);
}
__device__ __forceinline__ float fast_exp(float x) {
    return __builtin_amdgcn_exp2f(x * 1.4426950408889634f);
}

// ---------------------------------------------------------------------------
// Prep: transpose + convert weights to bf16.
// ---------------------------------------------------------------------------
__global__ __launch_bounds__(256) void prep_kernel(
    const float* __restrict__ kf, const float* __restrict__ kb,
    const float* __restrict__ rf, const float* __restrict__ rb,
    short* __restrict__ kT, short* __restrict__ rTf, short* __restrict__ rTb)
{
    int idx = blockIdx.x * 256 + threadIdx.x;   // 0 .. 1536*256-1
    int n = idx >> 8;
    int k = idx & 255;
    const float* src = (n < 768) ? kf : kb;
    int nn = (n < 768) ? n : (n - 768);
    kT[idx] = f2bf(src[k * 768 + nn]);
    if (n < 768) {
        rTf[idx] = f2bf(rf[k * 768 + n]);
        rTb[idx] = f2bf(rb[k * 768 + n]);
    }
}

// ---------------------------------------------------------------------------
// Projection GEMM: xw = x@kernel + bias0 (+bias1 folded for z,r).
// Output layout PERMUTED for the gru kernel's per-lane register loads:
//   per (dir): region16 (64MB): [bg(4)][t(1024)][w(16)][lane(64)][8 halves]
//                               (slots: xz i=0..3, xr i=0..3)
//              region8  (32MB, at +64MB): [bg][t][w][lane][4 halves] (xh i=0..3)
//   where b = bg*16 + hi_t*4 + i_t, lane = hi_t*16 + (cg&15), w = cg>>4.
// ---------------------------------------------------------------------------
__global__ __launch_bounds__(256) void proj_kernel(
    const float* __restrict__ x, const short* __restrict__ kT,
    const float* __restrict__ bias_f, const float* __restrict__ bias_b,
    char* __restrict__ xwp_f, char* __restrict__ xwp_b)
{
    __shared__ short lA[64][264];
    __shared__ short lB[128][264];

    const int tid = threadIdx.x;
    const int m0 = blockIdx.x * 64;        // 64 consecutive m = same batch row b
    const int n0 = blockIdx.y * 128;

    const int b_blk  = m0 >> 10;
    const int bg     = b_blk >> 4;
    const int rowg   = b_blk & 15;
    const int hi_t   = rowg >> 2;
    const int i_t    = rowg & 3;
    const int tbase  = m0 & 1023;

#pragma unroll
    for (int rep = 0; rep < 16; ++rep) {
        int lin = rep * 256 + tid;
        int r = lin >> 6;
        int c4 = lin & 63;
        float4 v = *(const float4*)(x + (size_t)(m0 + r) * 256 + c4 * 4);
        short4 s;
        s.x = f2bf(v.x); s.y = f2bf(v.y); s.z = f2bf(v.z); s.w = f2bf(v.w);
        *(short4*)&lA[r][c4 * 4] = s;
    }
#pragma unroll
    for (int rep = 0; rep < 16; ++rep) {
        int lin = rep * 256 + tid;
        int r = lin >> 5;
        int c8 = lin & 31;
        uint4 v = *(const uint4*)(kT + (size_t)(n0 + r) * 256 + c8 * 8);
        *(uint4*)&lB[r][c8 * 8] = v;
    }
    __syncthreads();

    const int w = tid >> 6, l = tid & 63;
    const int l15 = l & 15, hi = l >> 4;

    bf16x8 a[8];
#pragma unroll
    for (int kt = 0; kt < 8; ++kt)
        a[kt] = *(const bf16x8*)&lA[w * 16 + l15][kt * 32 + hi * 8];

#pragma unroll
    for (int j = 0; j < 8; ++j) {
        f32x4 acc = {0.f, 0.f, 0.f, 0.f};
#pragma unroll
        for (int kt = 0; kt < 8; ++kt) {
            bf16x8 b = *(const bf16x8*)&lB[j * 16 + l15][kt * 32 + hi * 8];
            acc = __builtin_amdgcn_mfma_f32_16x16x32_bf16(a[kt], b, acc, 0, 0, 0);
        }
        int ng = n0 + j * 16 + l15;
        int dirb = ng >= 768;
        int nn = ng - (dirb ? 768 : 0);
        const float* bias = dirb ? bias_b : bias_f;
        float badd = bias[nn] + ((nn < 512) ? bias[768 + nn] : 0.f);
        char* basep = dirb ? xwp_b : xwp_f;

        int g   = nn >> 8;           // 0=z, 1=r, 2=h
        int cg2 = nn & 255;
        int wt  = cg2 >> 4;
        int lane_t = hi_t * 16 + (cg2 & 15);

#pragma unroll
        for (int i = 0; i < 4; ++i) {
            int t = tbase + w * 16 + hi * 4 + i;     // time index of this row
            unsigned short hv = __builtin_bit_cast(unsigned short,
                                    __float2half(acc[i] + badd));
            if (g < 2) {
                *(unsigned short*)(basep + ((size_t)bg << 24) + ((size_t)t << 14)
                                   + (wt << 10) + (lane_t << 4) + ((g * 4 + i_t) << 1)) = hv;
            } else {
                *(unsigned short*)(basep + 67108864u + ((size_t)bg << 23) + ((size_t)t << 13)
                                   + (wt << 9) + (lane_t << 3) + (i_t << 1)) = hv;
            }
        }
    }
}

// ---------------------------------------------------------------------------
// Recurrence: 8 blocks (2 dirs x 4 groups of 16 batch rows), 1024 threads.
// Wave w owns h-columns [16w,16w+16).
//  - ALL 24 rec B-fragments register/AGPR-resident (96 regs/lane; launches at
//    16 waves/CU per R3 evidence). No per-step B LDS traffic.
//  - h state in MFMA A-FRAGMENT layout, double-buffered (stride-1 b128 reads).
//  - xw per-lane loads prefetched ONE STEP AHEAD into ping-pong registers;
//    xz/xr folded into MFMA accumulator init (az=xz, ar=xr, ah=b1h).
//  - gates: sigmoid-form tanh (no clamp; inf drains via rcp), h->bf16 via
//    v_cvt_pk_bf16_f32.
//  - ONE lgkm-only raw barrier per step.
// ---------------------------------------------------------------------------
#define GRU_STEP(PR, PW, XC16, XC8, XN16, XN8)                               \
  {                                                                          \
    XN16 = *(const uint4*)xp16;  xp16 += step16;                             \
    XN8  = *(const uint2*)xp8;   xp8  += step8;                              \
    const __half* hx  = (const __half*)&XC16;                                \
    const __half* hx8 = (const __half*)&XC8;                                 \
    f32x4 az, ar, ah;                                                        \
    _Pragma("unroll") for (int i = 0; i < 4; ++i) {                          \
      az[i] = __half2float(hx[i]);                                           \
      ar[i] = __half2float(hx[4 + i]);                                       \
      ah[i] = b1h;                                                           \
    }                                                                        \
    _Pragma("unroll") for (int kt = 0; kt < 8; ++kt) {                       \
      bf16x8 aq = *(const bf16x8*)((const char*)hfrag + (PR)*8192            \
                                   + kt * 1024 + l * 16);                    \
      az = __builtin_amdgcn_mfma_f32_16x16x32_bf16(aq, Bz[kt], az, 0,0,0);   \
      ar = __builtin_amdgcn_mfma_f32_16x16x32_bf16(aq, Br[kt], ar, 0,0,0);   \
      ah = __builtin_amdgcn_mfma_f32_16x16x32_bf16(aq, Bh[kt], ah, 0,0,0);   \
    }                                                                        \
    float hn[4];                                                             \
    _Pragma("unroll") for (int i = 0; i < 4; ++i) {                          \
      float zi  = fast_rcp(1.f + fast_exp(-az[i]));                          \
      float rri = fast_rcp(1.f + fast_exp(-ar[i]));                          \
      float xh  = __half2float(hx8[i]);                                      \
      float pre = xh + rri * ah[i];                                          \
      float sg  = fast_rcp(1.f + fast_exp(-2.f * pre));                      \
      float hh  = 2.f * sg - 1.f;                                            \
      float h2  = hh + zi * (hold[i] - hh);                                  \
      hold[i] = h2;  hn[i] = h2;                                             \
      opbase[i * 524288] = h2;                                               \
    }                                                                        \
    unsigned pk0, pk1;                                                       \
    asm("v_cvt_pk_bf16_f32 %0, %1, %2" : "=v"(pk0) : "v"(hn[0]), "v"(hn[1]));\
    asm("v_cvt_pk_bf16_f32 %0, %1, %2" : "=v"(pk1) : "v"(hn[2]), "v"(hn[3]));\
    {                                                                        \
      char* hb = (char*)hfrag + (PW)*8192 + wb;                              \
      *(short*)(hb)      = (short)(pk0 & 0xffff);                            \
      *(short*)(hb + 16) = (short)(pk0 >> 16);                               \
      *(short*)(hb + 32) = (short)(pk1 & 0xffff);                            \
      *(short*)(hb + 48) = (short)(pk1 >> 16);                               \
    }                                                                        \
    opbase += ostep;                                                         \
    asm volatile("s_waitcnt lgkmcnt(0)\n\ts_barrier" ::: "memory");          \
  }

__global__ __launch_bounds__(1024) void gru_kernel(
    const char* __restrict__ xwp_f, const char* __restrict__ xwp_b,
    const short* __restrict__ recT_f, const short* __restrict__ recT_b,
    const float* __restrict__ bias_f, const float* __restrict__ bias_b,
    float* __restrict__ out)
{
    __shared__ short hfrag[2][8][64][8];      // h in A-frag layout, 16KB

    const int tid = threadIdx.x;
    const int w = tid >> 6, l = tid & 63;
    const int l15 = l & 15, hi = l >> 4;
    const int dir = blockIdx.x >> 2;
    const int bg  = blockIdx.x & 3;
    const int b0  = bg * 16;

    const char*  xwp  = dir ? xwp_b  : xwp_f;
    const short* recT = dir ? recT_b : recT_f;
    const float* bias = dir ? bias_b : bias_f;

    const int cg = w * 16 + l15;
    const float b1h = bias[768 + 512 + cg];

    // zero both hfrag buffers (16KB = 1024 x int4)
    ((int4*)hfrag)[tid] = make_int4(0, 0, 0, 0);

    // rec-kernel B fragments -> registers/AGPRs (loop-invariant)
    const char* recTc = (const char*)recT;
    unsigned offz = (((unsigned)(cg)       * 256u) + hi * 8u) * 2u;
    unsigned offr = (((unsigned)(256 + cg) * 256u) + hi * 8u) * 2u;
    unsigned offh = (((unsigned)(512 + cg) * 256u) + hi * 8u) * 2u;
    bf16x8 Bz[8], Br[8], Bh[8];
#pragma unroll
    for (int kt = 0; kt < 8; ++kt) {
        Bz[kt] = *(const bf16x8*)(recTc + offz + kt * 64);
        Br[kt] = *(const bf16x8*)(recTc + offr + kt * 64);
        Bh[kt] = *(const bf16x8*)(recTc + offh + kt * 64);
    }

    // xw per-lane streaming pointers (permuted layout)
    const int t0 = dir ? 1023 : 0;
    const long step16 = dir ? -16384 : 16384;
    const long step8  = dir ? -8192  : 8192;
    const char* xp16 = xwp + ((size_t)bg << 24) + ((size_t)t0 << 14)
                       + (w << 10) + (l << 4);
    const char* xp8  = xwp + 67108864u + ((size_t)bg << 23) + ((size_t)t0 << 13)
                       + (w << 9) + (l << 3);

    // out: rows b0+hi*4+i, column dir*256+cg, time t
    const long ostep = dir ? -512 : 512;
    float* opbase = out + (size_t)(b0 + hi * 4) * 524288 + (size_t)t0 * 512
                    + (size_t)dir * 256 + cg;

    // h-write byte offset within an hfrag buffer (A-frag position of (row, cg))
    const unsigned wb = (unsigned)(cg >> 5) * 1024u
                      + ((((unsigned)cg >> 3) & 3u) * 16u) * 16u
                      + (unsigned)(hi * 4) * 16u + ((unsigned)(l15 & 7)) * 2u;

    // prologue: load xw(t0) into the A register set
    uint4 xA16, xB16;
    uint2 xA8,  xB8;
    xA16 = *(const uint4*)xp16;  xp16 += step16;
    xA8  = *(const uint2*)xp8;   xp8  += step8;

    f32x4 hold = {0.f, 0.f, 0.f, 0.f};
    __syncthreads();      // hfrag zeros visible

    for (int su = 0; su < 512; ++su) {
        GRU_STEP(0, 1, xA16, xA8, xB16, xB8)   // use A, prefetch B
        GRU_STEP(1, 0, xB16, xB8, xA16, xA8)   // use B, prefetch A
    }
    // final prefetch reads t=1024 / t=-1: lands inside d_ws regions, unused.
}

// ---------------------------------------------------------------------------
extern "C" void kernel_launch(void* const* d_in, const int* in_sizes, int n_in,
                              void* d_out, int out_size, void* d_ws, size_t ws_size,
                              hipStream_t stream) {
    const float* x   = (const float*)d_in[0];
    const float* kf  = (const float*)d_in[1];
    const float* rf  = (const float*)d_in[2];
    const float* bf_ = (const float*)d_in[3];
    const float* kb  = (const float*)d_in[4];
    const float* rb  = (const float*)d_in[5];
    const float* bb_ = (const float*)d_in[6];

    char* ws = (char*)d_ws;
    char* xwp_f = ws;                                 // 96MB permuted xw (fwd)
    char* xwp_b = ws + 100663296;                     // 96MB permuted xw (bwd)
    short* rTf  = (short*)(ws + 201326592);           // 768*256 bf16
    short* rTb  = (short*)(ws + 201719808);
    short* kT   = (short*)(ws + 202113024);           // 1536*256 bf16
    float* out  = (float*)d_out;

    hipLaunchKernelGGL(prep_kernel, dim3(1536), dim3(256), 0, stream,
                       kf, kb, rf, rb, kT, rTf, rTb);
    hipLaunchKernelGGL(proj_kernel, dim3(1024, 12), dim3(256), 0, stream,
                       x, kT, bf_, bb_, xwp_f, xwp_b);
    hipLaunchKernelGGL(gru_kernel, dim3(8), dim3(1024), 0, stream,
                       xwp_f, xwp_b, rTf, rTb, bf_, bb_, out);
}

// Round 8
// 1866.768 us; speedup vs baseline: 1.6935x; 1.6935x over previous
//
#include <hip/hip_runtime.h>
#include <hip/hip_fp16.h>
#include <hip/hip_bf16.h>

typedef __attribute__((ext_vector_type(8))) short bf16x8;
typedef __attribute__((ext_vector_type(4))) float f32x4;

__device__ __forceinline__ short f2bf(float f) {
    unsigned u = __builtin_bit_cast(unsigned, f);
    unsigned r = (u + 0x7FFFu + ((u >> 16) & 1u)) >> 16;
    return (short)r;
}
__device__ __forceinline__ float fast_rcp(float x) {
    return __builtin_amdgcn_rcpf(x);
}
__device__ __forceinline__ float fast_exp(float x) {
    return __builtin_amdgcn_exp2f(x * 1.4426950408889634f);
}

// ---------------------------------------------------------------------------
// Prep: transpose + convert weights to bf16.
// ---------------------------------------------------------------------------
__global__ __launch_bounds__(256) void prep_kernel(
    const float* __restrict__ kf, const float* __restrict__ kb,
    const float* __restrict__ rf, const float* __restrict__ rb,
    short* __restrict__ kT, short* __restrict__ rTf, short* __restrict__ rTb)
{
    int idx = blockIdx.x * 256 + threadIdx.x;   // 0 .. 1536*256-1
    int n = idx >> 8;
    int k = idx & 255;
    const float* src = (n < 768) ? kf : kb;
    int nn = (n < 768) ? n : (n - 768);
    kT[idx] = f2bf(src[k * 768 + nn]);
    if (n < 768) {
        rTf[idx] = f2bf(rf[k * 768 + n]);
        rTb[idx] = f2bf(rb[k * 768 + n]);
    }
}

// ---------------------------------------------------------------------------
// Projection GEMM: xw = x@kernel + bias0 (+bias1 folded for z,r).
// Output layout PERMUTED for the gru kernel's per-lane register loads:
//   per (dir): region16 (64MB): [bg(4)][t(1024)][w(16)][lane(64)][8 halves]
//                               (slots: xz i=0..3, xr i=0..3)
//              region8  (32MB, at +64MB): [bg][t][w][lane][4 halves] (xh i=0..3)
//   where b = bg*16 + hi_t*4 + i_t, lane = hi_t*16 + (cg&15), w = cg>>4.
// ---------------------------------------------------------------------------
__global__ __launch_bounds__(256) void proj_kernel(
    const float* __restrict__ x, const short* __restrict__ kT,
    const float* __restrict__ bias_f, const float* __restrict__ bias_b,
    char* __restrict__ xwp_f, char* __restrict__ xwp_b)
{
    __shared__ short lA[64][264];
    __shared__ short lB[128][264];

    const int tid = threadIdx.x;
    const int m0 = blockIdx.x * 64;        // 64 consecutive m = same batch row b
    const int n0 = blockIdx.y * 128;

    const int b_blk  = m0 >> 10;
    const int bg     = b_blk >> 4;
    const int rowg   = b_blk & 15;
    const int hi_t   = rowg >> 2;
    const int i_t    = rowg & 3;
    const int tbase  = m0 & 1023;

#pragma unroll
    for (int rep = 0; rep < 16; ++rep) {
        int lin = rep * 256 + tid;
        int r = lin >> 6;
        int c4 = lin & 63;
        float4 v = *(const float4*)(x + (size_t)(m0 + r) * 256 + c4 * 4);
        short4 s;
        s.x = f2bf(v.x); s.y = f2bf(v.y); s.z = f2bf(v.z); s.w = f2bf(v.w);
        *(short4*)&lA[r][c4 * 4] = s;
    }
#pragma unroll
    for (int rep = 0; rep < 16; ++rep) {
        int lin = rep * 256 + tid;
        int r = lin >> 5;
        int c8 = lin & 31;
        uint4 v = *(const uint4*)(kT + (size_t)(n0 + r) * 256 + c8 * 8);
        *(uint4*)&lB[r][c8 * 8] = v;
    }
    __syncthreads();

    const int w = tid >> 6, l = tid & 63;
    const int l15 = l & 15, hi = l >> 4;

    bf16x8 a[8];
#pragma unroll
    for (int kt = 0; kt < 8; ++kt)
        a[kt] = *(const bf16x8*)&lA[w * 16 + l15][kt * 32 + hi * 8];

#pragma unroll
    for (int j = 0; j < 8; ++j) {
        f32x4 acc = {0.f, 0.f, 0.f, 0.f};
#pragma unroll
        for (int kt = 0; kt < 8; ++kt) {
            bf16x8 b = *(const bf16x8*)&lB[j * 16 + l15][kt * 32 + hi * 8];
            acc = __builtin_amdgcn_mfma_f32_16x16x32_bf16(a[kt], b, acc, 0, 0, 0);
        }
        int ng = n0 + j * 16 + l15;
        int dirb = ng >= 768;
        int nn = ng - (dirb ? 768 : 0);
        const float* bias = dirb ? bias_b : bias_f;
        float badd = bias[nn] + ((nn < 512) ? bias[768 + nn] : 0.f);
        char* basep = dirb ? xwp_b : xwp_f;

        int g   = nn >> 8;           // 0=z, 1=r, 2=h
        int cg2 = nn & 255;
        int wt  = cg2 >> 4;
        int lane_t = hi_t * 16 + (cg2 & 15);

#pragma unroll
        for (int i = 0; i < 4; ++i) {
            int t = tbase + w * 16 + hi * 4 + i;     // time index of this row
            unsigned short hv = __builtin_bit_cast(unsigned short,
                                    __float2half(acc[i] + badd));
            if (g < 2) {
                *(unsigned short*)(basep + ((size_t)bg << 24) + ((size_t)t << 14)
                                   + (wt << 10) + (lane_t << 4) + ((g * 4 + i_t) << 1)) = hv;
            } else {
                *(unsigned short*)(basep + 67108864u + ((size_t)bg << 23) + ((size_t)t << 13)
                                   + (wt << 9) + (lane_t << 3) + (i_t << 1)) = hv;
            }
        }
    }
}

// ---------------------------------------------------------------------------
// Recurrence: 8 blocks (2 dirs x 4 groups of 16 batch rows), 1024 threads.
// Wave w owns h-columns [16w,16w+16).
//  - 21 of 24 rec B-fragments register-resident (84 regs/lane); 3 (Bh[5..7])
//    in LDS per-lane frag layout (48 b128 reads/step, conflict-free).
//    Total reg budget ~121 <= 128 @ 16 waves/CU (R7's 24-resident spilled).
//  - h state in MFMA A-FRAGMENT layout, double-buffered (stride-1 b128 reads).
//  - xw per-lane dwordx4+dwordx2 issued at step start, consumed post-MFMA
//    (latency hidden under MFMA phase) - R6's proven pattern.
//  - gates: sigmoid-form tanh (no clamp), h->bf16 via v_cvt_pk_bf16_f32.
//  - ONE lgkm-only raw barrier per step.
// ---------------------------------------------------------------------------
#define GRU_STEP(PR, PW)                                                     \
  {                                                                          \
    uint4  xv16 = *(const uint4*)xp16;  xp16 += step16;                      \
    uint2  xv8  = *(const uint2*)xp8;   xp8  += step8;                       \
    unsigned bbase = 0;                                                      \
    asm volatile("" : "+v"(bbase));   /* defeat cross-step LDS-read hoist */ \
    f32x4 az = {0.f,0.f,0.f,0.f}, ar = {0.f,0.f,0.f,0.f},                    \
          ah = {0.f,0.f,0.f,0.f};                                            \
    _Pragma("unroll") for (int kt = 0; kt < 8; ++kt) {                       \
      bf16x8 aq = *(const bf16x8*)((const char*)hfrag + (PR)*8192            \
                                   + kt * 1024 + l * 16);                    \
      bf16x8 bh;                                                             \
      if (kt < 5) bh = Bh[kt];                                               \
      else bh = *(const bf16x8*)((const char*)bfrag + bbase                  \
                                 + (kt - 5) * 16384 + w * 1024 + l * 16);    \
      az = __builtin_amdgcn_mfma_f32_16x16x32_bf16(aq, Bz[kt], az, 0,0,0);   \
      ar = __builtin_amdgcn_mfma_f32_16x16x32_bf16(aq, Br[kt], ar, 0,0,0);   \
      ah = __builtin_amdgcn_mfma_f32_16x16x32_bf16(aq, bh, ah, 0,0,0);       \
    }                                                                        \
    const __half* hx  = (const __half*)&xv16;                                \
    const __half* hx8 = (const __half*)&xv8;                                 \
    float hn[4];                                                             \
    _Pragma("unroll") for (int i = 0; i < 4; ++i) {                          \
      float zi  = fast_rcp(1.f + fast_exp(-(__half2float(hx[i]) + az[i])));  \
      float rri = fast_rcp(1.f + fast_exp(-(__half2float(hx[4+i]) + ar[i])));\
      float pre = __half2float(hx8[i]) + rri * (ah[i] + b1h);                \
      float sg  = fast_rcp(1.f + fast_exp(-2.f * pre));                      \
      float hh  = 2.f * sg - 1.f;                                            \
      float h2  = hh + zi * (hold[i] - hh);                                  \
      hold[i] = h2;  hn[i] = h2;                                             \
      opbase[i * 524288] = h2;                                               \
    }                                                                        \
    unsigned pk0, pk1;                                                       \
    asm("v_cvt_pk_bf16_f32 %0, %1, %2" : "=v"(pk0) : "v"(hn[0]), "v"(hn[1]));\
    asm("v_cvt_pk_bf16_f32 %0, %1, %2" : "=v"(pk1) : "v"(hn[2]), "v"(hn[3]));\
    {                                                                        \
      char* hb = (char*)hfrag + (PW)*8192 + wb;                              \
      *(short*)(hb)      = (short)(pk0 & 0xffff);                            \
      *(short*)(hb + 16) = (short)(pk0 >> 16);                               \
      *(short*)(hb + 32) = (short)(pk1 & 0xffff);                            \
      *(short*)(hb + 48) = (short)(pk1 >> 16);                               \
    }                                                                        \
    opbase += ostep;                                                         \
    asm volatile("s_waitcnt lgkmcnt(0)\n\ts_barrier" ::: "memory");          \
  }

__global__ __launch_bounds__(1024) void gru_kernel(
    const char* __restrict__ xwp_f, const char* __restrict__ xwp_b,
    const short* __restrict__ recT_f, const short* __restrict__ recT_b,
    const float* __restrict__ bias_f, const float* __restrict__ bias_b,
    float* __restrict__ out)
{
    __shared__ short hfrag[2][8][64][8];      // h in A-frag layout, 16KB
    __shared__ short bfrag[3][16][64][8];     // offloaded Bh[5..7], 48KB

    const int tid = threadIdx.x;
    const int w = tid >> 6, l = tid & 63;
    const int l15 = l & 15, hi = l >> 4;
    const int dir = blockIdx.x >> 2;
    const int bg  = blockIdx.x & 3;
    const int b0  = bg * 16;

    const char*  xwp  = dir ? xwp_b  : xwp_f;
    const short* recT = dir ? recT_b : recT_f;
    const float* bias = dir ? bias_b : bias_f;

    const int cg = w * 16 + l15;
    const float b1h = bias[768 + 512 + cg];

    // zero both hfrag buffers (16KB = 1024 x int4)
    ((int4*)hfrag)[tid] = make_int4(0, 0, 0, 0);

    // rec-kernel B fragments: 21 to registers, 3 (Bh[5..7]) to LDS
    const char* recTc = (const char*)recT;
    unsigned offz = (((unsigned)(cg)       * 256u) + hi * 8u) * 2u;
    unsigned offr = (((unsigned)(256 + cg) * 256u) + hi * 8u) * 2u;
    unsigned offh = (((unsigned)(512 + cg) * 256u) + hi * 8u) * 2u;
    bf16x8 Bz[8], Br[8], Bh[5];
#pragma unroll
    for (int kt = 0; kt < 8; ++kt) {
        Bz[kt] = *(const bf16x8*)(recTc + offz + kt * 64);
        Br[kt] = *(const bf16x8*)(recTc + offr + kt * 64);
    }
#pragma unroll
    for (int kt = 0; kt < 5; ++kt)
        Bh[kt] = *(const bf16x8*)(recTc + offh + kt * 64);
#pragma unroll
    for (int kt = 5; kt < 8; ++kt) {
        bf16x8 tmp = *(const bf16x8*)(recTc + offh + kt * 64);
        *(bf16x8*)((char*)bfrag + (kt - 5) * 16384 + w * 1024 + l * 16) = tmp;
    }

    // xw per-lane streaming pointers (permuted layout)
    const int t0 = dir ? 1023 : 0;
    const long step16 = dir ? -16384 : 16384;
    const long step8  = dir ? -8192  : 8192;
    const char* xp16 = xwp + ((size_t)bg << 24) + ((size_t)t0 << 14)
                       + (w << 10) + (l << 4);
    const char* xp8  = xwp + 67108864u + ((size_t)bg << 23) + ((size_t)t0 << 13)
                       + (w << 9) + (l << 3);

    // out: rows b0+hi*4+i, column dir*256+cg, time t
    const long ostep = dir ? -512 : 512;
    float* opbase = out + (size_t)(b0 + hi * 4) * 524288 + (size_t)t0 * 512
                    + (size_t)dir * 256 + cg;

    // h-write byte offset within an hfrag buffer (A-frag position of (row, cg))
    const unsigned wb = (unsigned)(cg >> 5) * 1024u
                      + ((((unsigned)cg >> 3) & 3u) * 16u) * 16u
                      + (unsigned)(hi * 4) * 16u + ((unsigned)(l15 & 7)) * 2u;

    f32x4 hold = {0.f, 0.f, 0.f, 0.f};
    __syncthreads();      // hfrag zeros + bfrag writes visible

    for (int su = 0; su < 512; ++su) {
        GRU_STEP(0, 1)
        GRU_STEP(1, 0)
    }
}

// ---------------------------------------------------------------------------
extern "C" void kernel_launch(void* const* d_in, const int* in_sizes, int n_in,
                              void* d_out, int out_size, void* d_ws, size_t ws_size,
                              hipStream_t stream) {
    const float* x   = (const float*)d_in[0];
    const float* kf  = (const float*)d_in[1];
    const float* rf  = (const float*)d_in[2];
    const float* bf_ = (const float*)d_in[3];
    const float* kb  = (const float*)d_in[4];
    const float* rb  = (const float*)d_in[5];
    const float* bb_ = (const float*)d_in[6];

    char* ws = (char*)d_ws;
    char* xwp_f = ws;                                 // 96MB permuted xw (fwd)
    char* xwp_b = ws + 100663296;                     // 96MB permuted xw (bwd)
    short* rTf  = (short*)(ws + 201326592);           // 768*256 bf16
    short* rTb  = (short*)(ws + 201719808);
    short* kT   = (short*)(ws + 202113024);           // 1536*256 bf16
    float* out  = (float*)d_out;

    hipLaunchKernelGGL(prep_kernel, dim3(1536), dim3(256), 0, stream,
                       kf, kb, rf, rb, kT, rTf, rTb);
    hipLaunchKernelGGL(proj_kernel, dim3(1024, 12), dim3(256), 0, stream,
                       x, kT, bf_, bb_, xwp_f, xwp_b);
    hipLaunchKernelGGL(gru_kernel, dim3(8), dim3(1024), 0, stream,
                       xwp_f, xwp_b, rTf, rTb, bf_, bb_, out);
}